// Round 1
// baseline (246.598 us; speedup 1.0000x reference)
//
#include <hip/hip_runtime.h>

// SPP: out = concat([x, maxpool5(x), maxpool9(x), maxpool13(x)], ch) on NHWC
// x: (16, 64, 64, 512) fp32.  out: (16, 64, 64, 2048) fp32.
//
// Strategy: memory-bound fused single pass.
//   mp5  = 5x5 stride-1 SAME max pool (separable: vertical reg-ring, horizontal LDS)
//   mp9  = max of mp5 at (h±2, w±2)            [4 points, clamped indices]
//   mp13 = max of mp5 at (h+{-4,0,4}, w+{-4,0,4}) [9 points, clamped indices]
// Clamping is exact: clamped 5-windows still tile the 9/13-window, and
// duplicate valid entries are idempotent under max. Vertical OOB handled with
// -inf register entries (exact).
//
// Block: (n, 16-channel group, 32-row chunk). 256 thr = 64 w * 4 float4 slots.
// lane<->channel mapping => all global ops are 64B-contiguous per 4 lanes.

constexpr int H  = 64;
constexpr int W  = 64;
constexpr int C  = 512;
constexpr int TH = 32;          // output rows per block

__device__ __forceinline__ float4 f4max(float4 a, float4 b) {
    return make_float4(fmaxf(a.x, b.x), fmaxf(a.y, b.y),
                       fmaxf(a.z, b.z), fmaxf(a.w, b.w));
}

__global__ __launch_bounds__(256, 4)
void spp_kernel(const float* __restrict__ x, float* __restrict__ out) {
    __shared__ float4 v5row[W * 4];        //  4 KB: vertical-max5 row [w*4+c4]
    __shared__ float4 ring[9][W * 4];      // 36 KB: last 9 mp5 rows, slot = row%9

    const int t     = threadIdx.x;         // 0..255
    const int c4    = t & 3;               // float4 slot within 16-ch group
    const int w     = t >> 2;              // 0..63
    const int chunk = blockIdx.x;          // 0..1
    const int cg    = blockIdx.y;          // 0..31
    const int n     = blockIdx.z;          // 0..15
    const int h0    = chunk * TH;
    const int cb    = cg * 16 + c4 * 4;    // channel offset (floats)

    const float* xb = x   + (size_t)n * H * W * C + cb;
    float*       ob = out + (size_t)n * H * W * (4 * C) + cb;

    const float NEG = -__builtin_inff();

    auto loadx = [&](int row) -> float4 {
        if ((unsigned)row < (unsigned)H)
            return *reinterpret_cast<const float4*>(xb + (size_t)(row * W + w) * C);
        return make_float4(NEG, NEG, NEG, NEG);
    };

    // clamped LDS column indices (precomputed, loop-invariant)
    const int wc  = t;                                  // w*4 + c4
    const int wm1 = max(w - 1, 0) * 4 + c4;
    const int wm2 = max(w - 2, 0) * 4 + c4;
    const int wm4 = max(w - 4, 0) * 4 + c4;
    const int wp1 = min(w + 1, W - 1) * 4 + c4;
    const int wp2 = min(w + 2, W - 1) * 4 + c4;
    const int wp4 = min(w + 4, W - 1) * 4 + c4;

    // vertical register ring: rows r-2..r+2 live in x0..x4 at step r
    const int s0 = (h0 >= 4) ? (h0 - 4) : 0;
    float4 x0, x1, x2, x3, x4;
    x1 = loadx(s0 - 2);
    x2 = loadx(s0 - 1);
    x3 = loadx(s0);
    x4 = loadx(s0 + 1);
    x0 = x1;  // filled by first shift

    for (int r = s0; r < h0 + TH + 4; ++r) {
        // --- phase A: advance vertical ring, compute v5 row r ---
        x0 = x1; x1 = x2; x2 = x3; x3 = x4;
        x4 = loadx(r + 2);
        const bool rvalid = (r < H);       // r >= 0 by construction
        if (rvalid) {
            v5row[wc] = f4max(f4max(f4max(x0, x1), f4max(x2, x3)), x4);
        }
        __syncthreads();

        // --- phase B: horizontal max5 -> mp5 row r; store copy + mp5 ---
        if (rvalid) {
            float4 m = f4max(f4max(f4max(v5row[wm2], v5row[wm1]),
                                   f4max(v5row[wc],  v5row[wp1])),
                             v5row[wp2]);
            ring[r % 9][wc] = m;
            if (r >= h0 && r < h0 + TH) {
                float* o = ob + (size_t)(r * W + w) * (4 * C);
                *reinterpret_cast<float4*>(o)     = x2;   // x copy (row r)
                *reinterpret_cast<float4*>(o + C) = m;    // mp5
            }
        }
        __syncthreads();

        // --- phase C: mp9 / mp13 for row q = r-4 from mp5 ring ---
        const int q = r - 4;
        if (q >= h0 && q < h0 + TH) {
            const int rm2 = (max(q - 2, 0))     % 9;
            const int rp2 = (min(q + 2, H - 1)) % 9;
            const int rm4 = (max(q - 4, 0))     % 9;
            const int rp4 = (min(q + 4, H - 1)) % 9;
            const int rq  = q % 9;

            float4 mp9 = f4max(f4max(ring[rm2][wm2], ring[rm2][wp2]),
                               f4max(ring[rp2][wm2], ring[rp2][wp2]));

            float4 a  = f4max(f4max(ring[rm4][wm4], ring[rm4][wc]), ring[rm4][wp4]);
            float4 b  = f4max(f4max(ring[rq ][wm4], ring[rq ][wc]), ring[rq ][wp4]);
            float4 c_ = f4max(f4max(ring[rp4][wm4], ring[rp4][wc]), ring[rp4][wp4]);
            float4 mp13 = f4max(f4max(a, b), c_);

            float* o = ob + (size_t)(q * W + w) * (4 * C);
            *reinterpret_cast<float4*>(o + 2 * C) = mp9;
            *reinterpret_cast<float4*>(o + 3 * C) = mp13;
        }
        // next iteration's first barrier separates phase C reads from the
        // ring-slot overwrite in the next phase B (slot (r+1)%9 == (q-4)%9).
    }
}

extern "C" void kernel_launch(void* const* d_in, const int* in_sizes, int n_in,
                              void* d_out, int out_size, void* d_ws, size_t ws_size,
                              hipStream_t stream) {
    const float* x = (const float*)d_in[0];
    float* out = (float*)d_out;

    const int N = in_sizes[0] / (H * W * C);   // 16

    dim3 grid(H / TH, C / 16, N);              // (2, 32, 16) = 1024 blocks
    dim3 block(256);
    spp_kernel<<<grid, block, 0, stream>>>(x, out);
}

// Round 2
// 172.129 us; speedup vs baseline: 1.4326x; 1.4326x over previous
//
#include <hip/hip_runtime.h>

// SPP: out = concat([x, maxpool5(x), maxpool9(x), maxpool13(x)], ch) on NHWC
// x: (16, 64, 64, 512) fp32 -> out: (16, 64, 64, 2048) fp32.
//
// Exact decomposition (index-clamped, duplicates idempotent under max):
//   v5[row][w]  = max over x rows clamp(row-2..row+2)          (vertical, per col)
//   mp5[r]      = 5-col  hmax of v5[r]
//   h9[row]     = 9-col  hmax of v5[row];  mp9[q]  = max(h9[q-2], h9[q+2])
//   h13[row]    = 13-col hmax of v5[row];  mp13[q] = max(h13[q-4], h13[q], h13[q+4])
// Register rings carry h9 (depth 7) and h13 (depth 9); x ring depth 5.
// LDS holds only one double-buffered, col-padded v5 row -> 1 barrier/iter.
//
// Store coalescing: 32 channels/block => every float4 store is part of a full
// aligned 128B line segment (8 lanes x 16B), eliminating partial-line writes.

constexpr int H  = 64;
constexpr int W  = 64;
constexpr int C  = 512;
constexpr int TH = 32;                    // output rows per block
constexpr int SLOTS = 8;                  // float4 slots per w (32 channels/block)
constexpr int PAD   = 6;                  // col halo, replicated (clamp semantics)
constexpr int LROW  = (W + 2 * PAD) * SLOTS;

__device__ __forceinline__ float4 f4max(float4 a, float4 b) {
    return make_float4(fmaxf(a.x, b.x), fmaxf(a.y, b.y),
                       fmaxf(a.z, b.z), fmaxf(a.w, b.w));
}

__global__ __launch_bounds__(512, 4)
void spp_kernel(const float* __restrict__ x, float* __restrict__ out) {
    __shared__ float4 v5buf[2][LROW];     // 2 x 9.5 KB

    const int t  = threadIdx.x;           // 0..511
    const int c4 = t & (SLOTS - 1);       // float4 slot (channel/4 within group)
    const int w  = t >> 3;                // 0..63
    const int h0 = blockIdx.x * TH;
    const int cb = blockIdx.y * 32 + c4 * 4;
    const int n  = blockIdx.z;

    const float* xb = x   + (size_t)n * H * W * C + cb;
    float*       ob = out + (size_t)n * H * W * (4 * C) + cb;

    auto loadx = [&](int row) -> float4 {
        row = min(max(row, 0), H - 1);    // row clamp: exact (idempotent dups)
        return *reinterpret_cast<const float4*>(xb + (size_t)(row * W + w) * C);
    };

    // x ring: after the in-loop shift at iter r, x0..x4 = rows r-2..r+2
    float4 x0, x1, x2, x3, x4;
    x1 = loadx(h0 - 6);
    x2 = loadx(h0 - 5);
    x3 = loadx(h0 - 4);
    x4 = loadx(h0 - 3);
    x0 = x1;

    const float4 z = make_float4(0.f, 0.f, 0.f, 0.f);
    // h9 ring: pre-insert at iter r, g6 = h9[r-1] ... g0 = h9[r-7]
    float4 g0=z, g1=z, g2=z, g3=z, g4=z, g5=z, g6=z;
    // h13 ring: pre-insert at iter r, t8 = h13[r-1] ... t0 = h13[r-8]
    float4 t0=z, t1=z, t2=z, t3=z, t4=z, t5=z, t6=z, t7=z, t8=z;

    const int wb = (w + PAD) * SLOTS + c4;   // LDS write index (own col)

    for (int r = h0 - 4; r < h0 + TH + 4; ++r) {
        // ---- vertical 5-max for row r ----
        x0 = x1; x1 = x2; x2 = x3; x3 = x4;
        x4 = loadx(r + 2);
        float4 v5 = f4max(f4max(f4max(x0, x1), f4max(x2, x3)), x4);

        float4* buf = v5buf[r & 1];
        buf[wb] = v5;
        if (w == 0) {                      // replicate left halo (clamp cols)
            #pragma unroll
            for (int d = 1; d <= PAD; ++d) buf[wb - d * SLOTS] = v5;
        }
        if (w == W - 1) {                  // replicate right halo
            #pragma unroll
            for (int d = 1; d <= PAD; ++d) buf[wb + d * SLOTS] = v5;
        }
        __syncthreads();

        // ---- horizontal maxes of v5[r] via 13 immediate-offset taps ----
        const float4* rbuf = &v5buf[r & 1][t];   // tap k -> col (w - 6 + k)
        float4 a0 = rbuf[4 * SLOTS], a1 = rbuf[5 * SLOTS], a2 = rbuf[6 * SLOTS],
               a3 = rbuf[7 * SLOTS], a4 = rbuf[8 * SLOTS];
        float4 m5 = f4max(f4max(f4max(a0, a1), f4max(a2, a3)), a4);

        float4 b0 = rbuf[2 * SLOTS], b1 = rbuf[3 * SLOTS],
               b2 = rbuf[9 * SLOTS], b3 = rbuf[10 * SLOTS];
        float4 h9 = f4max(m5, f4max(f4max(b0, b1), f4max(b2, b3)));

        float4 c0 = rbuf[0],          c1 = rbuf[1 * SLOTS],
               c2 = rbuf[11 * SLOTS], c3 = rbuf[12 * SLOTS];
        float4 h13 = f4max(h9, f4max(f4max(c0, c1), f4max(c2, c3)));

        // ---- outputs ----
        // x copy + mp5 at row r (x2 = row r, m5 = mp5[r])
        if ((unsigned)(r - h0) < (unsigned)TH) {
            float* o = ob + (size_t)(r * W + w) * (4 * C);
            *reinterpret_cast<float4*>(o)     = x2;
            *reinterpret_cast<float4*>(o + C) = m5;
        }
        // mp9/mp13 at row q = r-4 (ring taps pre-insert: g5=h9[r-2], g1=h9[r-6],
        // t5=h13[r-4], t1=h13[r-8]; fresh h13 = h13[r])
        const int q = r - 4;
        if ((unsigned)(q - h0) < (unsigned)TH) {
            float4 mp9  = f4max(g5, g1);
            float4 mp13 = f4max(h13, f4max(t5, t1));
            float* o = ob + (size_t)(q * W + w) * (4 * C);
            *reinterpret_cast<float4*>(o + 2 * C) = mp9;
            *reinterpret_cast<float4*>(o + 3 * C) = mp13;
        }

        // ---- push rings ----
        g0 = g1; g1 = g2; g2 = g3; g3 = g4; g4 = g5; g5 = g6; g6 = h9;
        t0 = t1; t1 = t2; t2 = t3; t3 = t4; t4 = t5; t5 = t6; t6 = t7; t7 = t8; t8 = h13;
    }
}

extern "C" void kernel_launch(void* const* d_in, const int* in_sizes, int n_in,
                              void* d_out, int out_size, void* d_ws, size_t ws_size,
                              hipStream_t stream) {
    const float* x = (const float*)d_in[0];
    float* out = (float*)d_out;

    const int N = in_sizes[0] / (H * W * C);   // 16

    dim3 grid(H / TH, C / 32, N);              // (2, 16, 16) = 512 blocks = 2/CU
    dim3 block(512);
    spp_kernel<<<grid, block, 0, stream>>>(x, out);
}

// Round 4
// 109.870 us; speedup vs baseline: 2.2444x; 1.5667x over previous
//
#include <hip/hip_runtime.h>

// SPP: out = concat([x, maxpool5(x), maxpool9(x), maxpool13(x)], ch) on NHWC
// x: (16, 64, 64, 512) fp32 -> out: (16, 64, 64, 2048) fp32.
//
// Exact decomposition (index-clamped loads; duplicates idempotent under max):
//   v5[r]  = vertical 5-max of x rows clamp(r-2..r+2)   (register ring, depth 5)
//   m5[r]  = 5-col hmax(v5[r])      -> mp5 row r
//   h9[r]  = 9-col hmax(v5[r]);  mp9[q=r-2]  = max(h9[r-4], h9[r])       (ring 4)
//   h13[r] = 13-col hmax(v5[r]); mp13[q=r-4] = max(h13[r-8], h13[r-4], h13[r]) (ring 8)
//
// Perf structure:
//  - RAW s_barrier + lgkmcnt(0) only: global stores and the prefetched x-row
//    load stay in flight across barriers (no vmcnt(0) drain per iteration).
//  - 1-row x prefetch distance; double-buffered LDS v5 row, 1 barrier/iter.
//  - 32 channels/block: every 8-lane store group = one full aligned 128B line.
//  - Non-temporal stores: keep x L3-resident under 537 MB of streaming writes.
//  - launch_bounds(512,2): 256-VGPR cap, no spills.

constexpr int H  = 64;
constexpr int W  = 64;
constexpr int C  = 512;
constexpr int TH = 32;                    // output rows per block
constexpr int SLOTS = 8;                  // float4 slots per w (32 ch/block)
constexpr int PAD   = 6;                  // replicated col halo (clamp semantics)
constexpr int LROW  = (W + 2 * PAD) * SLOTS;

typedef float nf4 __attribute__((ext_vector_type(4)));   // native vec for NT store

__device__ __forceinline__ float4 f4max(float4 a, float4 b) {
    return make_float4(fmaxf(a.x, b.x), fmaxf(a.y, b.y),
                       fmaxf(a.z, b.z), fmaxf(a.w, b.w));
}

__device__ __forceinline__ void st_nt(float* p, float4 v) {
    nf4 q = {v.x, v.y, v.z, v.w};
    __builtin_nontemporal_store(q, reinterpret_cast<nf4*>(p));
}

__global__ __launch_bounds__(512, 2)
void spp_kernel(const float* __restrict__ x, float* __restrict__ out) {
    __shared__ float4 v5buf[2][LROW];     // 2 x 9.5 KB

    const int t  = threadIdx.x;           // 0..511
    const int c4 = t & (SLOTS - 1);
    const int w  = t >> 3;                // 0..63
    const int h0 = blockIdx.x * TH;
    const int cb = blockIdx.y * 32 + c4 * 4;
    const int n  = blockIdx.z;

    const float* xb = x   + (size_t)n * H * W * C + cb;
    float*       ob = out + (size_t)n * H * W * (4 * C) + cb;

    auto loadx = [&](int row) -> float4 {
        row = min(max(row, 0), H - 1);
        return *reinterpret_cast<const float4*>(xb + (size_t)(row * W + w) * C);
    };

    const int wb = (w + PAD) * SLOTS + c4;   // LDS write index (own col)

    // x ring: at body R, x0..x4 = rows R-2..R+2. xn = prefetch of row R+3.
    float4 x0 = loadx(h0 - 6), x1 = loadx(h0 - 5), x2 = loadx(h0 - 4),
           x3 = loadx(h0 - 3), x4 = loadx(h0 - 2);
    float4 xn;

    const float4 z = make_float4(0.f, 0.f, 0.f, 0.f);
    float4 e0 = z, e1 = z, e2 = z, e3 = z;                     // h9[R-4..R-1]
    float4 d0 = z, d1 = z, d2 = z, d3 = z,
           d4 = z, d5 = z, d6 = z, d7 = z;                     // h13[R-8..R-1]

    auto body = [&](int R, float4* buf) {
        xn = loadx(R + 3);                             // prefetch, in flight
        float4 v5 = f4max(f4max(f4max(x0, x1), f4max(x2, x3)), x4);
        buf[wb] = v5;
        if (w == 0) {
            #pragma unroll
            for (int k = 1; k <= PAD; ++k) buf[wb - k * SLOTS] = v5;
        }
        if (w == W - 1) {
            #pragma unroll
            for (int k = 1; k <= PAD; ++k) buf[wb + k * SLOTS] = v5;
        }
        const bool rowok = (unsigned)(R - h0) < (unsigned)TH;
        if (rowok)                                     // x copy: pre-barrier
            st_nt(ob + (size_t)(R * W + w) * (4 * C), x2);

        asm volatile("s_waitcnt lgkmcnt(0)" ::: "memory");
        __builtin_amdgcn_s_barrier();                  // raw: no vmcnt drain
        __builtin_amdgcn_sched_barrier(0);

        const float4* rb = buf + t;                    // tap k -> col w-6+k
        float4 m5 = f4max(v5, f4max(rb[4 * SLOTS], rb[5 * SLOTS]));
        m5 = f4max(m5, f4max(rb[7 * SLOTS], rb[8 * SLOTS]));
        float4 h9 = f4max(m5, f4max(f4max(rb[2 * SLOTS], rb[3 * SLOTS]),
                                    f4max(rb[9 * SLOTS], rb[10 * SLOTS])));
        float4 h13 = f4max(h9, f4max(f4max(rb[0],           rb[1 * SLOTS]),
                                     f4max(rb[11 * SLOTS], rb[12 * SLOTS])));

        if (rowok)
            st_nt(ob + (size_t)(R * W + w) * (4 * C) + C, m5);
        if ((unsigned)(R - 2 - h0) < (unsigned)TH)
            st_nt(ob + (size_t)((R - 2) * W + w) * (4 * C) + 2 * C,
                  f4max(e0, h9));
        if ((unsigned)(R - 4 - h0) < (unsigned)TH)
            st_nt(ob + (size_t)((R - 4) * W + w) * (4 * C) + 3 * C,
                  f4max(f4max(d0, d4), h13));

        e0 = e1; e1 = e2; e2 = e3; e3 = h9;
        d0 = d1; d1 = d2; d2 = d3; d3 = d4; d4 = d5; d5 = d6; d6 = d7; d7 = h13;
        x0 = x1; x1 = x2; x2 = x3; x3 = x4; x4 = xn;
    };

    for (int r = h0 - 4; r < h0 + TH + 4; r += 2) {    // 40 bodies, static bufs
        body(r,     v5buf[0]);
        body(r + 1, v5buf[1]);
    }
}

extern "C" void kernel_launch(void* const* d_in, const int* in_sizes, int n_in,
                              void* d_out, int out_size, void* d_ws, size_t ws_size,
                              hipStream_t stream) {
    const float* x = (const float*)d_in[0];
    float* out = (float*)d_out;

    const int N = in_sizes[0] / (H * W * C);   // 16

    dim3 grid(H / TH, C / 32, N);              // (2, 16, 16) = 512 blocks
    dim3 block(512);
    spp_kernel<<<grid, block, 0, stream>>>(x, out);
}